// Round 4
// baseline (194.133 us; speedup 1.0000x reference)
//
#include <hip/hip_runtime.h>

#define N_NODES 100000
#define N_EDGES 800000
#define EHALF (N_EDGES / 2)
#define H 128
#define MAX_Z 1000
#define N_GRAPHS 500
#define ELL_CAP 32
#define EB 1563                  // edge blocks: ceil(400000/256)
#define CTR1 64
#define AG_GRID 2048             // grid-stride blocks for k_agg0 (8 blocks/CU)
#define LB_GRID 1040             // grid-stride blocks for k_layerB

typedef __attribute__((ext_vector_type(8))) short bf16x8;
typedef __attribute__((ext_vector_type(4))) float f32x4;

__device__ __forceinline__ unsigned short f2bf(float f) {
    union { float f; unsigned u; } x; x.f = f;
    unsigned r = x.u + 0x7fffu + ((x.u >> 16) & 1u);   // RTNE
    return (unsigned short)(r >> 16);
}
__device__ __forceinline__ float bf2f(unsigned short u) {
    return __uint_as_float((unsigned)u << 16);
}
__device__ __forceinline__ int clampid(int p) {       // poison (0xAA..) is negative
    return (p < 0 || p >= N_NODES) ? 0 : p;
}

// wave-aggregated list push (1 counter atomic per wave with >=1 winner)
__device__ __forceinline__ void wpush(bool need, int val, int* ctr, int* list) {
    unsigned long long b = __ballot(need);
    if (b == 0) return;
    int lane = threadIdx.x & 63;
    int leader = __builtin_ctzll(b);
    int pre = __popcll(b & ((1ull << lane) - 1ull));
    int base = 0;
    if (lane == leader) base = atomicAdd(ctr, __popcll(b));
    base = __shfl(base, leader);
    if (need) list[base + pre] = val;
}

// ---- pass 1 (single structural pass over edges), plus hoisted matrix work:
//  [0,EB)        : full ELL build (fill cursor = exact masked in-degree) and
//                  inline N1 discovery: masked center-edges dedup-push source
//  [EB,EB+4)     : push the 1000 center nodes into N1 (deduped)
//  [EB+4,EB+67)  : T0 = bf16(ztab) @ bf16(W0)  (layer-0 GEMM on z-table)
//  [EB+67,EB+83) : pack W1,W2 into bf16 MFMA B-fragments
__global__ __launch_bounds__(256) void k_front(const int* __restrict__ esrc,
                                               const int* __restrict__ edst,
                                               const int* __restrict__ mask,
                                               int* fill, int* ell, int* f1,
                                               int* list1, int* ctrs,
                                               const float* __restrict__ ztab,
                                               const float* __restrict__ W0,
                                               const float* __restrict__ W1,
                                               const float* __restrict__ W2,
                                               unsigned short* Wp,
                                               unsigned short* T0) {
    int b = blockIdx.x, tid = threadIdx.x;
    if (b < EB) {
        int e = b * 256 + tid;
        bool p0 = false, p1 = false;
        int s0 = 0, s1 = 0;
        if (e < EHALF) {
            int m0 = mask[e], m1 = mask[e + EHALF];
            int d0 = edst[e], d1 = edst[e + EHALF];
            s0 = esrc[e]; s1 = esrc[e + EHALF];
            if (m0) {
                int q = atomicAdd(&fill[d0], 1);
                if (q < ELL_CAP) ell[(size_t)d0 * ELL_CAP + q] = s0;
                if (d0 % 200 < 2) p0 = (atomicExch(&f1[s0], 1) == 0);
            }
            if (m1) {
                int q = atomicAdd(&fill[d1], 1);
                if (q < ELL_CAP) ell[(size_t)d1 * ELL_CAP + q] = s1;
                if (d1 % 200 < 2) p1 = (atomicExch(&f1[s1], 1) == 0);
            }
        }
        wpush(p0, s0, &ctrs[CTR1], list1);
        wpush(p1, s1, &ctrs[CTR1], list1);
    } else if (b < EB + 4) {
        int i = (b - EB) * 256 + tid;
        bool need = false; int v = 0;
        if (i < 2 * N_GRAPHS) {
            v = (i >> 1) * 200 + (i & 1);
            need = (atomicExch(&f1[v], 1) == 0);
        }
        wpush(need, v, &ctrs[CTR1], list1);
    } else if (b < EB + 4 + 63) {
        // T0 GEMM tile t (0..62): fp32 ztab/W0 -> bf16 in-register -> MFMA
        int t = b - EB - 4;
        int lane = tid & 63, wv = tid >> 6;
        int m = lane & 15, quad = lane >> 4;
        int row = t * 16 + m;
        const float* ar = ztab + (size_t)(row < MAX_Z ? row : 0) * H + quad * 8;
        bf16x8 A[4];
#pragma unroll
        for (int kk = 0; kk < 4; kk++) {
            float4 u  = *(const float4*)(ar + kk * 32);
            float4 v4 = *(const float4*)(ar + kk * 32 + 4);
            bf16x8 aa;
            aa[0] = (short)f2bf(u.x);  aa[1] = (short)f2bf(u.y);
            aa[2] = (short)f2bf(u.z);  aa[3] = (short)f2bf(u.w);
            aa[4] = (short)f2bf(v4.x); aa[5] = (short)f2bf(v4.y);
            aa[6] = (short)f2bf(v4.z); aa[7] = (short)f2bf(v4.w);
            A[kk] = aa;
        }
#pragma unroll
        for (int c2 = 0; c2 < 2; c2++) {
            int c = wv * 2 + c2;
            int n = c * 16 + m;
            f32x4 acc = (f32x4){0.f, 0.f, 0.f, 0.f};
#pragma unroll
            for (int kt = 0; kt < 4; kt++) {
                bf16x8 bb;
#pragma unroll
                for (int j = 0; j < 8; j++)
                    bb[j] = (short)f2bf(W0[(size_t)(kt * 32 + quad * 8 + j) * H + n]);
                acc = __builtin_amdgcn_mfma_f32_16x16x32_bf16(A[kt], bb, acc, 0, 0, 0);
            }
            int r0 = t * 16 + quad * 4;
#pragma unroll
            for (int i2 = 0; i2 < 4; i2++) {
                int r = r0 + i2;
                if (r < MAX_Z) T0[(size_t)r * H + n] = f2bf(acc[i2]);
            }
        }
    } else {
        int bb = b - EB - 4 - 63;                      // 0..15: pack W1, W2
        int wi = 1 + (bb >> 3);
        const float* W = (wi == 1) ? W1 : W2;
        int t = (bb & 7) * 256 + tid;                  // 0..2047
        int l = t & 63, kt = (t >> 6) & 3, c = t >> 8;
        int quad = l >> 4, n = c * 16 + (l & 15);
        unsigned short o[8];
#pragma unroll
        for (int j = 0; j < 8; j++) o[j] = f2bf(W[(kt * 32 + quad * 8 + j) * H + n]);
        ushort4 lo = { o[0], o[1], o[2], o[3] }, hi = { o[4], o[5], o[6], o[7] };
        unsigned short* dst = Wp + (size_t)wi * 16384 + (size_t)t * 8;
        *(ushort4*)(dst)     = lo;
        *(ushort4*)(dst + 4) = hi;
    }
}

// ---- layer 0 over ALL nodes: T0-row aggregation + bias + ReLU -> xb ------
// one wave per row; dense row index (no list); ell row read is one 128B line
__global__ __launch_bounds__(256) void k_agg0(const int* __restrict__ z,
                                              const unsigned short* __restrict__ T0,
                                              const int* __restrict__ ell,
                                              const int* __restrict__ fill,
                                              const float* __restrict__ bias,
                                              unsigned short* xb) {
    int tid = threadIdx.x, lane = tid & 63, wv = tid >> 6;
    int l2 = lane * 2;
    float2 bv = *(const float2*)(bias + l2);
    for (int v = blockIdx.x * 4 + wv; v < N_NODES; v += AG_GRID * 4) {
        int ntrue = fill[v];
        int px = 0;
        if (lane < ELL_CAP) px = ell[(size_t)v * ELL_CAP + lane];
        px = clampid(px);              // poison-safe; lanes >= n unused
        int zx = z[px];
        int fx = fill[px];
        int zv = z[v];
        int n = ntrue > ELL_CAP ? ELL_CAP : ntrue;
        float dv = rsqrtf(1.0f + (float)ntrue);
        float pc = (lane < n) ? rsqrtf(1.0f + (float)fx) * dv : 0.f;
        float sc = dv * dv;
        ushort2 xs = *(const ushort2*)(T0 + (size_t)zv * H + l2);
        float ax = sc * bf2f(xs.x) + bv.x;
        float ay = sc * bf2f(xs.y) + bv.y;
        int k = 0;
        for (; k + 3 < n; k += 4) {
            int z0 = __shfl(zx, k),   z1 = __shfl(zx, k + 1);
            int z2 = __shfl(zx, k + 2), z3 = __shfl(zx, k + 3);
            float c0 = __shfl(pc, k),   c1 = __shfl(pc, k + 1);
            float c2 = __shfl(pc, k + 2), c3 = __shfl(pc, k + 3);
            ushort2 m0 = *(const ushort2*)(T0 + (size_t)z0 * H + l2);
            ushort2 m1 = *(const ushort2*)(T0 + (size_t)z1 * H + l2);
            ushort2 m2 = *(const ushort2*)(T0 + (size_t)z2 * H + l2);
            ushort2 m3 = *(const ushort2*)(T0 + (size_t)z3 * H + l2);
            ax += c0 * bf2f(m0.x) + c1 * bf2f(m1.x) + c2 * bf2f(m2.x) + c3 * bf2f(m3.x);
            ay += c0 * bf2f(m0.y) + c1 * bf2f(m1.y) + c2 * bf2f(m2.y) + c3 * bf2f(m3.y);
        }
        for (; k < n; k++) {
            int zz = __shfl(zx, k); float c = __shfl(pc, k);
            ushort2 m0 = *(const ushort2*)(T0 + (size_t)zz * H + l2);
            ax += c * bf2f(m0.x); ay += c * bf2f(m0.y);
        }
        ushort2 o;
        o.x = f2bf(fmaxf(ax, 0.f));
        o.y = f2bf(fmaxf(ay, 0.f));
        *(ushort2*)(xb + (size_t)v * H + l2) = o;
    }
}

// ---- fused layer B: agg from bf16 xin + GEMM + bias + ReLU -> xout -------
__global__ __launch_bounds__(512) void k_layerB(const unsigned short* __restrict__ xin,
                                                const int* __restrict__ ell,
                                                const int* __restrict__ fill,
                                                const int* __restrict__ list,
                                                const int* countp,
                                                const unsigned short* __restrict__ Wp,
                                                const float* __restrict__ bias,
                                                unsigned short* xout) {
    __shared__ unsigned short yt[16][136];
    int count = *countp;
    int tid = threadIdx.x, lane = tid & 63, wv = tid >> 6;   // wv 0..7
    int l2 = lane * 2;
    int m = lane & 15, quad = lane >> 4;

    for (int t = blockIdx.x; t * 16 < count; t += LB_GRID) {
        for (int q = 0; q < 2; q++) {
            int r = t * 16 + wv * 2 + q;
            float ax = 0.f, ay = 0.f;
            if (r < count) {
                int v = list[r];
                int ntrue = fill[v];
                int px = 0;
                if (lane < ELL_CAP) px = ell[(size_t)v * ELL_CAP + lane];
                px = clampid(px);
                int fx = fill[px];
                ushort2 xs = *(const ushort2*)(xin + (size_t)v * H + l2);
                int n = ntrue > ELL_CAP ? ELL_CAP : ntrue;
                float dv = rsqrtf(1.0f + (float)ntrue);
                float pc = (lane < n) ? rsqrtf(1.0f + (float)fx) * dv : 0.f;
                float sc = dv * dv;
                ax = sc * bf2f(xs.x); ay = sc * bf2f(xs.y);
                int k = 0;
                for (; k + 3 < n; k += 4) {
                    int s0 = __shfl(px, k),   s1 = __shfl(px, k + 1);
                    int s2 = __shfl(px, k + 2), s3 = __shfl(px, k + 3);
                    float c0 = __shfl(pc, k),   c1 = __shfl(pc, k + 1);
                    float c2 = __shfl(pc, k + 2), c3 = __shfl(pc, k + 3);
                    ushort2 m0 = *(const ushort2*)(xin + (size_t)s0 * H + l2);
                    ushort2 m1 = *(const ushort2*)(xin + (size_t)s1 * H + l2);
                    ushort2 m2 = *(const ushort2*)(xin + (size_t)s2 * H + l2);
                    ushort2 m3 = *(const ushort2*)(xin + (size_t)s3 * H + l2);
                    ax += c0 * bf2f(m0.x) + c1 * bf2f(m1.x) + c2 * bf2f(m2.x) + c3 * bf2f(m3.x);
                    ay += c0 * bf2f(m0.y) + c1 * bf2f(m1.y) + c2 * bf2f(m2.y) + c3 * bf2f(m3.y);
                }
                for (; k < n; k++) {
                    int s = __shfl(px, k); float c = __shfl(pc, k);
                    ushort2 m0 = *(const ushort2*)(xin + (size_t)s * H + l2);
                    ax += c * bf2f(m0.x); ay += c * bf2f(m0.y);
                }
            }
            ushort2 o; o.x = f2bf(ax); o.y = f2bf(ay);
            *(ushort2*)&yt[wv * 2 + q][l2] = o;
        }
        __syncthreads();

        bf16x8 a0 = *(const bf16x8*)&yt[m][quad * 8];
        bf16x8 a1 = *(const bf16x8*)&yt[m][32 + quad * 8];
        bf16x8 a2 = *(const bf16x8*)&yt[m][64 + quad * 8];
        bf16x8 a3 = *(const bf16x8*)&yt[m][96 + quad * 8];
        const unsigned short* bp = Wp + ((size_t)(wv * 4) * 64 + lane) * 8;
        bf16x8 b0 = *(const bf16x8*)(bp);
        bf16x8 b1 = *(const bf16x8*)(bp + 64 * 8);
        bf16x8 b2 = *(const bf16x8*)(bp + 128 * 8);
        bf16x8 b3 = *(const bf16x8*)(bp + 192 * 8);
        f32x4 a = (f32x4){0.f, 0.f, 0.f, 0.f};
        a = __builtin_amdgcn_mfma_f32_16x16x32_bf16(a0, b0, a, 0, 0, 0);
        a = __builtin_amdgcn_mfma_f32_16x16x32_bf16(a1, b1, a, 0, 0, 0);
        a = __builtin_amdgcn_mfma_f32_16x16x32_bf16(a2, b2, a, 0, 0, 0);
        a = __builtin_amdgcn_mfma_f32_16x16x32_bf16(a3, b3, a, 0, 0, 0);

        int r0 = t * 16 + quad * 4;
        int col = wv * 16 + m;
        float bv = bias[col];
#pragma unroll
        for (int i = 0; i < 4; i++) {
            int r = r0 + i;
            if (r < count)
                xout[(size_t)list[r] * H + col] = f2bf(fmaxf(a[i] + bv, 0.f));
        }
        __syncthreads();   // protect yt before next stride iteration
    }
}

// ---- fused layer 2 + head: agg at centers + GEMM + hadamard + MLP --------
__global__ __launch_bounds__(256) void k_layer2(const unsigned short* __restrict__ xin,
                                                const int* __restrict__ ell,
                                                const int* __restrict__ fill,
                                                const unsigned short* __restrict__ Wp,
                                                const float* b2,
                                                const float* l1w, const float* l1b,
                                                const float* l2w, const float* l2b,
                                                float* out) {
    __shared__ unsigned short yt[16][136];
    __shared__ float ct[16][132];
    int t = blockIdx.x;                       // 0..62
    int tid = threadIdx.x, lane = tid & 63, wv = tid >> 6;
    int l2 = lane * 2;

    for (int q = 0; q < 4; q++) {
        int idx = t * 16 + wv * 4 + q;
        float ax = 0.f, ay = 0.f;
        if (idx < 2 * N_GRAPHS) {
            int v = (idx >> 1) * 200 + (idx & 1);
            int ntrue = fill[v];
            int px = 0;
            if (lane < ELL_CAP) px = ell[(size_t)v * ELL_CAP + lane];
            px = clampid(px);
            int fx = fill[px];
            ushort2 xs = *(const ushort2*)(xin + (size_t)v * H + l2);
            int n = ntrue > ELL_CAP ? ELL_CAP : ntrue;
            float dv = rsqrtf(1.0f + (float)ntrue);
            float pc = (lane < n) ? rsqrtf(1.0f + (float)fx) * dv : 0.f;
            float sc = dv * dv;
            ax = sc * bf2f(xs.x); ay = sc * bf2f(xs.y);
            int k = 0;
            for (; k + 3 < n; k += 4) {
                int s0 = __shfl(px, k),   s1 = __shfl(px, k + 1);
                int s2 = __shfl(px, k + 2), s3 = __shfl(px, k + 3);
                float c0 = __shfl(pc, k),   c1 = __shfl(pc, k + 1);
                float c2 = __shfl(pc, k + 2), c3 = __shfl(pc, k + 3);
                ushort2 m0 = *(const ushort2*)(xin + (size_t)s0 * H + l2);
                ushort2 m1 = *(const ushort2*)(xin + (size_t)s1 * H + l2);
                ushort2 m2 = *(const ushort2*)(xin + (size_t)s2 * H + l2);
                ushort2 m3 = *(const ushort2*)(xin + (size_t)s3 * H + l2);
                ax += c0 * bf2f(m0.x) + c1 * bf2f(m1.x) + c2 * bf2f(m2.x) + c3 * bf2f(m3.x);
                ay += c0 * bf2f(m0.y) + c1 * bf2f(m1.y) + c2 * bf2f(m2.y) + c3 * bf2f(m3.y);
            }
            for (; k < n; k++) {
                int s = __shfl(px, k); float c = __shfl(pc, k);
                ushort2 m0 = *(const ushort2*)(xin + (size_t)s * H + l2);
                ax += c * bf2f(m0.x); ay += c * bf2f(m0.y);
            }
        }
        ushort2 o; o.x = f2bf(ax); o.y = f2bf(ay);
        *(ushort2*)&yt[wv * 4 + q][l2] = o;
    }
    __syncthreads();

    int m = lane & 15, quad = lane >> 4;
    bf16x8 a0 = *(const bf16x8*)&yt[m][quad * 8];
    bf16x8 a1 = *(const bf16x8*)&yt[m][32 + quad * 8];
    bf16x8 a2 = *(const bf16x8*)&yt[m][64 + quad * 8];
    bf16x8 a3 = *(const bf16x8*)&yt[m][96 + quad * 8];

#pragma unroll
    for (int c2 = 0; c2 < 2; c2++) {
        int c = wv * 2 + c2;
        const unsigned short* bp = Wp + ((size_t)(c * 4) * 64 + lane) * 8;
        bf16x8 b0 = *(const bf16x8*)(bp);
        bf16x8 b1 = *(const bf16x8*)(bp + 64 * 8);
        bf16x8 bb = *(const bf16x8*)(bp + 128 * 8);
        bf16x8 b3 = *(const bf16x8*)(bp + 192 * 8);
        f32x4 a = (f32x4){0.f, 0.f, 0.f, 0.f};
        a = __builtin_amdgcn_mfma_f32_16x16x32_bf16(a0, b0, a, 0, 0, 0);
        a = __builtin_amdgcn_mfma_f32_16x16x32_bf16(a1, b1, a, 0, 0, 0);
        a = __builtin_amdgcn_mfma_f32_16x16x32_bf16(a2, bb, a, 0, 0, 0);
        a = __builtin_amdgcn_mfma_f32_16x16x32_bf16(a3, b3, a, 0, 0, 0);
        int col = c * 16 + m;
        float bv = b2[col];
#pragma unroll
        for (int i = 0; i < 4; i++)
            ct[quad * 4 + i][col] = a[i] + bv;
    }
    __syncthreads();

    // head: 8 graphs per block; 32 threads per graph, 4 output feats each
    int gl = tid >> 5, jq = tid & 31, j4 = jq * 4;
    int g = t * 8 + gl;
    float4 h = *(const float4*)(l1b + j4);
    const float* r0 = &ct[2 * gl][0];
    const float* r1 = &ct[2 * gl + 1][0];
#pragma unroll 4
    for (int k = 0; k < H; k++) {
        float pk = r0[k] * r1[k];
        float4 wv4 = *(const float4*)(l1w + (size_t)k * H + j4);
        h.x += pk * wv4.x; h.y += pk * wv4.y;
        h.z += pk * wv4.z; h.w += pk * wv4.w;
    }
    float4 l2v = *(const float4*)(l2w + j4);
    float s = fmaxf(h.x, 0.f) * l2v.x + fmaxf(h.y, 0.f) * l2v.y +
              fmaxf(h.z, 0.f) * l2v.z + fmaxf(h.w, 0.f) * l2v.w;
#pragma unroll
    for (int d = 16; d > 0; d >>= 1) s += __shfl_xor(s, d, 32);
    if (jq == 0 && g < N_GRAPHS) out[g] = s + l2b[0];
}

extern "C" void kernel_launch(void* const* d_in, const int* in_sizes, int n_in,
                              void* d_out, int out_size, void* d_ws, size_t ws_size,
                              hipStream_t stream) {
    const int*   z    = (const int*)d_in[0];
    const int*   esrc = (const int*)d_in[1];
    const int*   edst = ((const int*)d_in[1]) + N_EDGES;
    const int*   mask = (const int*)d_in[3];
    const float* ztab = (const float*)d_in[4];
    const float* W0   = (const float*)d_in[5];
    const float* b0   = (const float*)d_in[6];
    const float* W1   = (const float*)d_in[7];
    const float* b1   = (const float*)d_in[8];
    const float* W2   = (const float*)d_in[9];
    const float* b2   = (const float*)d_in[10];
    const float* l1w  = (const float*)d_in[11];
    const float* l1b  = (const float*)d_in[12];
    const float* l2w  = (const float*)d_in[13];
    const float* l2b  = (const float*)d_in[14];
    float* out = (float*)d_out;

    char* w = (char*)d_ws;
    size_t o = 0;
    auto carve = [&](size_t bytes) { char* p = w + o; o = (o + bytes + 255) & ~(size_t)255; return p; };
    // zero-group first: one memset covers fill + f1 + counters
    int*            fill  = (int*)carve((size_t)N_NODES * 4);
    int*            f1    = (int*)carve((size_t)N_NODES * 4);
    int*            ctrs  = (int*)carve(512);
    const size_t zero_span = o;
    int*            ell   = (int*)carve((size_t)N_NODES * ELL_CAP * 4);
    int*            list1 = (int*)carve((size_t)N_NODES * 4);
    unsigned short* xb    = (unsigned short*)carve((size_t)N_NODES * H * 2);
    unsigned short* xc    = (unsigned short*)carve((size_t)N_NODES * H * 2);
    unsigned short* Wp    = (unsigned short*)carve((size_t)3 * 16384 * 2);
    unsigned short* T0    = (unsigned short*)carve((size_t)MAX_Z * H * 2);

    hipMemsetAsync(d_ws, 0, zero_span, stream);
    // pass 1: full ELL + inline N1 discovery + T0 GEMM + W pack
    k_front<<<EB + 4 + 63 + 16, 256, 0, stream>>>(esrc, edst, mask, fill, ell,
                                                  f1, list1, ctrs,
                                                  ztab, W0, W1, W2, Wp, T0);
    // layer 0 over ALL nodes (no frontier machinery): T0-row agg -> xb
    k_agg0<<<AG_GRID, 256, 0, stream>>>(z, T0, ell, fill, b0, xb);
    // layer 1 (N1 rows): read xb, write xc
    k_layerB<<<LB_GRID, 512, 0, stream>>>(xb, ell, fill, list1, &ctrs[CTR1],
                                          Wp + 16384, b1, xc);
    // layer 2 + pooling + MLP head (reads xc)
    k_layer2<<<63, 256, 0, stream>>>(xc, ell, fill, Wp + 32768, b2,
                                     l1w, l1b, l2w, l2b, out);
}

// Round 5
// 149.628 us; speedup vs baseline: 1.2974x; 1.2974x over previous
//
#include <hip/hip_runtime.h>

#define N_NODES 100000
#define N_EDGES 800000
#define H 128
#define MAX_Z 1000
#define N_GRAPHS 500
#define ELL_CAP 32
#define SB 782                   // edge scan blocks: ceil(800000/(256*4))
#define SSTRIDE (SB * 256)       // 200192 threads, 4 edges each
#define SCAP 66                  // 2 centers + 2*32 neighbors

typedef __attribute__((ext_vector_type(8))) short bf16x8;
typedef __attribute__((ext_vector_type(4))) float f32x4;

__device__ __forceinline__ unsigned short f2bf(float f) {
    union { float f; unsigned u; } x; x.f = f;
    unsigned r = x.u + 0x7fffu + ((x.u >> 16) & 1u);   // RTNE
    return (unsigned short)(r >> 16);
}
__device__ __forceinline__ float bf2f(unsigned short u) {
    return __uint_as_float((unsigned)u << 16);
}
__device__ __forceinline__ int clampid(int p) {       // poison (0xAA..) is negative
    return (p < 0 || p >= N_NODES) ? 0 : p;
}

// ---- k_scan: ELL build with 4-edge ILP + T0 GEMM + W1 pack ---------------
//  [0,SB)        : 4 edges/thread; independent atomicAdds issued together so
//                  the RMW round-trips pipeline (round-4: 2 dependent chains
//                  per thread -> 58 us, latency-bound at VALUBusy 1.2%)
//  [SB,SB+63)    : T0 = bf16(ztab) @ bf16(W0)
//  [SB+63,SB+71) : pack W1 into bf16 MFMA B-fragments
__global__ __launch_bounds__(256) void k_scan(const int* __restrict__ esrc,
                                              const int* __restrict__ edst,
                                              const int* __restrict__ mask,
                                              int* fill, int* ell,
                                              const float* __restrict__ ztab,
                                              const float* __restrict__ W0,
                                              const float* __restrict__ W1,
                                              unsigned short* Wp,
                                              unsigned short* T0) {
    int b = blockIdx.x, tid = threadIdx.x;
    if (b < SB) {
        int e0 = b * 256 + tid;
        int e1 = e0 + SSTRIDE, e2 = e0 + 2 * SSTRIDE, e3 = e0 + 3 * SSTRIDE;
        int m0 = mask[e0], m1 = mask[e1], m2 = mask[e2];
        int m3 = (e3 < N_EDGES) ? mask[e3] : 0;
        int d0 = edst[e0], d1 = edst[e1], d2 = edst[e2];
        int d3 = (e3 < N_EDGES) ? edst[e3] : 0;
        int s0 = esrc[e0], s1 = esrc[e1], s2 = esrc[e2];
        int s3 = (e3 < N_EDGES) ? esrc[e3] : 0;
        int q0 = 0, q1 = 0, q2 = 0, q3 = 0;
        if (m0) q0 = atomicAdd(&fill[d0], 1);
        if (m1) q1 = atomicAdd(&fill[d1], 1);
        if (m2) q2 = atomicAdd(&fill[d2], 1);
        if (m3) q3 = atomicAdd(&fill[d3], 1);
        if (m0 && q0 < ELL_CAP) ell[(size_t)d0 * ELL_CAP + q0] = s0;
        if (m1 && q1 < ELL_CAP) ell[(size_t)d1 * ELL_CAP + q1] = s1;
        if (m2 && q2 < ELL_CAP) ell[(size_t)d2 * ELL_CAP + q2] = s2;
        if (m3 && q3 < ELL_CAP) ell[(size_t)d3 * ELL_CAP + q3] = s3;
    } else if (b < SB + 63) {
        // T0 GEMM tile t (0..62): fp32 ztab/W0 -> bf16 in-register -> MFMA
        int t = b - SB;
        int lane = tid & 63, wv = tid >> 6;
        int m = lane & 15, quad = lane >> 4;
        int row = t * 16 + m;
        const float* ar = ztab + (size_t)(row < MAX_Z ? row : 0) * H + quad * 8;
        bf16x8 A[4];
#pragma unroll
        for (int kk = 0; kk < 4; kk++) {
            float4 u  = *(const float4*)(ar + kk * 32);
            float4 v4 = *(const float4*)(ar + kk * 32 + 4);
            bf16x8 aa;
            aa[0] = (short)f2bf(u.x);  aa[1] = (short)f2bf(u.y);
            aa[2] = (short)f2bf(u.z);  aa[3] = (short)f2bf(u.w);
            aa[4] = (short)f2bf(v4.x); aa[5] = (short)f2bf(v4.y);
            aa[6] = (short)f2bf(v4.z); aa[7] = (short)f2bf(v4.w);
            A[kk] = aa;
        }
#pragma unroll
        for (int c2 = 0; c2 < 2; c2++) {
            int c = wv * 2 + c2;
            int n = c * 16 + m;
            f32x4 acc = (f32x4){0.f, 0.f, 0.f, 0.f};
#pragma unroll
            for (int kt = 0; kt < 4; kt++) {
                bf16x8 bb;
#pragma unroll
                for (int j = 0; j < 8; j++)
                    bb[j] = (short)f2bf(W0[(size_t)(kt * 32 + quad * 8 + j) * H + n]);
                acc = __builtin_amdgcn_mfma_f32_16x16x32_bf16(A[kt], bb, acc, 0, 0, 0);
            }
            int r0 = t * 16 + quad * 4;
#pragma unroll
            for (int i2 = 0; i2 < 4; i2++) {
                int r = r0 + i2;
                if (r < MAX_Z) T0[(size_t)r * H + n] = f2bf(acc[i2]);
            }
        }
    } else {
        int bb = b - SB - 63;                          // 0..7: pack W1
        int t = bb * 256 + tid;                        // 0..2047
        int l = t & 63, kt = (t >> 6) & 3, c = t >> 8;
        int quad = l >> 4, n = c * 16 + (l & 15);
        unsigned short o[8];
#pragma unroll
        for (int j = 0; j < 8; j++) o[j] = f2bf(W1[(kt * 32 + quad * 8 + j) * H + n]);
        ushort4 lo = { o[0], o[1], o[2], o[3] }, hi = { o[4], o[5], o[6], o[7] };
        unsigned short* dst = Wp + (size_t)t * 8;
        *(ushort4*)(dst)     = lo;
        *(ushort4*)(dst + 4) = hi;
    }
}

// ---- paired x1 evaluation: two nodes' layer-0 rows, loads interleaved ----
// x1[u] = relu( dv_u^2 * T0[z[u]] + sum_nbr coef * T0[z[nbr]] + b0 )
// lanes >= fill-cursor contribute coef 0 (poison ELL entries clamped to 0).
__device__ __forceinline__ void x1_eval2(const int* __restrict__ z,
                                         const unsigned short* __restrict__ T0,
                                         const int* __restrict__ ell,
                                         const int* __restrict__ fill,
                                         int u0, int nt0, int u1, int nt1,
                                         int lane, int l2, float2 bv,
                                         float& r0x, float& r0y,
                                         float& r1x, float& r1y) {
    int na = nt0 > ELL_CAP ? ELL_CAP : nt0;
    int nb = nt1 > ELL_CAP ? ELL_CAP : nt1;
    float dva = rsqrtf(1.0f + (float)nt0);
    float dvb = rsqrtf(1.0f + (float)nt1);
    int pa = (lane < ELL_CAP) ? ell[(size_t)u0 * ELL_CAP + lane] : 0;
    int pb = (lane < ELL_CAP) ? ell[(size_t)u1 * ELL_CAP + lane] : 0;
    pa = clampid(pa); pb = clampid(pb);
    int za = z[pa], zb = z[pb];
    int fa = fill[pa], fb = fill[pb];
    int zu0 = z[u0], zu1 = z[u1];
    float pca = (lane < na) ? rsqrtf(1.0f + (float)fa) * dva : 0.f;
    float pcb = (lane < nb) ? rsqrtf(1.0f + (float)fb) * dvb : 0.f;
    ushort2 xa = *(const ushort2*)(T0 + (size_t)zu0 * H + l2);
    ushort2 xc = *(const ushort2*)(T0 + (size_t)zu1 * H + l2);
    r0x = dva * dva * bf2f(xa.x) + bv.x;
    r0y = dva * dva * bf2f(xa.y) + bv.y;
    r1x = dvb * dvb * bf2f(xc.x) + bv.x;
    r1y = dvb * dvb * bf2f(xc.y) + bv.y;
    int kmax = na > nb ? na : nb;
    int k = 0;
    for (; k + 1 < kmax; k += 2) {
        int za0 = __shfl(za, k), za1 = __shfl(za, k + 1);
        int zb0 = __shfl(zb, k), zb1 = __shfl(zb, k + 1);
        float ca0 = __shfl(pca, k), ca1 = __shfl(pca, k + 1);
        float cb0 = __shfl(pcb, k), cb1 = __shfl(pcb, k + 1);
        ushort2 A0 = *(const ushort2*)(T0 + (size_t)za0 * H + l2);
        ushort2 A1 = *(const ushort2*)(T0 + (size_t)za1 * H + l2);
        ushort2 B0 = *(const ushort2*)(T0 + (size_t)zb0 * H + l2);
        ushort2 B1 = *(const ushort2*)(T0 + (size_t)zb1 * H + l2);
        r0x += ca0 * bf2f(A0.x) + ca1 * bf2f(A1.x);
        r0y += ca0 * bf2f(A0.y) + ca1 * bf2f(A1.y);
        r1x += cb0 * bf2f(B0.x) + cb1 * bf2f(B1.x);
        r1y += cb0 * bf2f(B0.y) + cb1 * bf2f(B1.y);
    }
    if (k < kmax) {
        int za0 = __shfl(za, k), zb0 = __shfl(zb, k);
        float ca0 = __shfl(pca, k), cb0 = __shfl(pcb, k);
        ushort2 A0 = *(const ushort2*)(T0 + (size_t)za0 * H + l2);
        ushort2 B0 = *(const ushort2*)(T0 + (size_t)zb0 * H + l2);
        r0x += ca0 * bf2f(A0.x); r0y += ca0 * bf2f(A0.y);
        r1x += cb0 * bf2f(B0.x); r1y += cb0 * bf2f(B0.y);
    }
    r0x = fmaxf(r0x, 0.f); r0y = fmaxf(r0y, 0.f);
    r1x = fmaxf(r1x, 0.f); r1y = fmaxf(r1y, 0.f);
}

// ---- k_fused: per-graph full back half ------------------------------------
// S = {c0, c1, nbrs(c0), nbrs(c1)}; x2[S] via on-the-fly x1 recompute + W1
// MFMA; then y2/x3 at the 2 centers (f32 VALU) + hadamard + MLP head.
__global__ __launch_bounds__(512) void k_fused(const int* __restrict__ z,
                                               const unsigned short* __restrict__ T0,
                                               const int* __restrict__ ell,
                                               const int* __restrict__ fill,
                                               const unsigned short* __restrict__ Wp1,
                                               const float* __restrict__ b0,
                                               const float* __restrict__ b1,
                                               const float* __restrict__ W2,
                                               const float* __restrict__ b2,
                                               const float* __restrict__ l1w,
                                               const float* __restrict__ l1b,
                                               const float* __restrict__ l2w,
                                               const float* __restrict__ l2b,
                                               float* __restrict__ out) {
    __shared__ float x2s[SCAP][132];
    __shared__ unsigned short yt[16][136];
    __shared__ float y2s[2][128];
    __shared__ float x3s[2][128];
    __shared__ int Slist[SCAP];
    __shared__ float Scoef[SCAP];
    __shared__ int n0s, n1s, scnts;
    __shared__ float sc0s, sc1s;
    __shared__ float hpart[2];

    int g = blockIdx.x;
    int tid = threadIdx.x, lane = tid & 63, wv = tid >> 6;   // 8 waves
    int l2 = lane * 2;
    int c0 = g * 200;
    float2 bv = *(const float2*)(b0 + l2);

    // ---- phase 0 (wave 0): build S + y2 coefficients ----
    if (wv == 0) {
        int half = lane >> 5, li = lane & 31;
        int c = c0 + half;
        int ntc = fill[c];
        int nc = ntc > ELL_CAP ? ELL_CAP : ntc;
        float dvc = rsqrtf(1.0f + (float)ntc);
        int u = (li < nc) ? ell[(size_t)c * ELL_CAP + li] : 0;
        u = clampid(u);
        int fu = fill[u];
        int n0v = __shfl(nc, 0), n1v = __shfl(nc, 32);
        int base = 2 + (half ? n0v : 0);
        if (li < nc) {
            Slist[base + li] = u;
            Scoef[base + li] = rsqrtf(1.0f + (float)fu) * dvc;
        }
        if (lane == 0)  { Slist[0] = c;  n0s = n0v; sc0s = dvc * dvc; scnts = 2 + n0v + n1v; }
        if (lane == 32) { Slist[1] = c;  n1s = n1v; sc1s = dvc * dvc; }
    }
    __syncthreads();
    const int scnt = scnts;

    // ---- phase 1: x2[S] = relu( y1(S) @ W1 + b1 ), tiles of 16 rows ----
    int m = lane & 15, quad = lane >> 4;
    int tiles = (scnt + 15) >> 4;
    for (int t = 0; t < tiles; ++t) {
        for (int q = 0; q < 2; q++) {
            int r = t * 16 + wv * 2 + q;
            float ax = 0.f, ay = 0.f;
            if (r < scnt) {
                int v = Slist[r];
                int ntv = fill[v];
                int nv = ntv > ELL_CAP ? ELL_CAP : ntv;
                float dv = rsqrtf(1.0f + (float)ntv);
                int px = (lane < ELL_CAP) ? ell[(size_t)v * ELL_CAP + lane] : 0;
                px = clampid(px);
                int fx = fill[px];
                float pc = (lane < nv) ? rsqrtf(1.0f + (float)fx) * dv : 0.f;
                // pair 0: (self, nbr0)
                {
                    int u1 = __shfl(px, 0); int f1v = __shfl(fx, 0);
                    float cu = __shfl(pc, 0);
                    float r0x, r0y, r1x, r1y;
                    x1_eval2(z, T0, ell, fill, v, ntv, u1, f1v,
                             lane, l2, bv, r0x, r0y, r1x, r1y);
                    ax = dv * dv * r0x + cu * r1x;
                    ay = dv * dv * r0y + cu * r1y;
                }
                for (int k = 1; k < nv; k += 2) {
                    int ua = __shfl(px, k);     int fav = __shfl(fx, k);
                    float ca = __shfl(pc, k);
                    int kb = (k + 1 < nv) ? k + 1 : k;     // pad with dup (coef 0 if k+1>=nv)
                    int ub = __shfl(px, kb);    int fbv = __shfl(fx, kb);
                    float cb = (k + 1 < nv) ? __shfl(pc, k + 1) : 0.f;
                    float r0x, r0y, r1x, r1y;
                    x1_eval2(z, T0, ell, fill, ua, fav, ub, fbv,
                             lane, l2, bv, r0x, r0y, r1x, r1y);
                    ax += ca * r0x + cb * r1x;
                    ay += ca * r0y + cb * r1y;
                }
            }
            ushort2 o; o.x = f2bf(ax); o.y = f2bf(ay);
            *(ushort2*)&yt[wv * 2 + q][l2] = o;
        }
        __syncthreads();
        bf16x8 a0 = *(const bf16x8*)&yt[m][quad * 8];
        bf16x8 a1 = *(const bf16x8*)&yt[m][32 + quad * 8];
        bf16x8 a2 = *(const bf16x8*)&yt[m][64 + quad * 8];
        bf16x8 a3 = *(const bf16x8*)&yt[m][96 + quad * 8];
        const unsigned short* bp = Wp1 + ((size_t)(wv * 4) * 64 + lane) * 8;
        bf16x8 b0f = *(const bf16x8*)(bp);
        bf16x8 b1f = *(const bf16x8*)(bp + 512);
        bf16x8 b2f = *(const bf16x8*)(bp + 1024);
        bf16x8 b3f = *(const bf16x8*)(bp + 1536);
        f32x4 a = (f32x4){0.f, 0.f, 0.f, 0.f};
        a = __builtin_amdgcn_mfma_f32_16x16x32_bf16(a0, b0f, a, 0, 0, 0);
        a = __builtin_amdgcn_mfma_f32_16x16x32_bf16(a1, b1f, a, 0, 0, 0);
        a = __builtin_amdgcn_mfma_f32_16x16x32_bf16(a2, b2f, a, 0, 0, 0);
        a = __builtin_amdgcn_mfma_f32_16x16x32_bf16(a3, b3f, a, 0, 0, 0);
        int r0 = t * 16 + quad * 4;
        int col = wv * 16 + m;
        float bb1 = b1[col];
#pragma unroll
        for (int i2 = 0; i2 < 4; i2++) {
            int r = r0 + i2;
            if (r < scnt) x2s[r][col] = fmaxf(a[i2] + bb1, 0.f);
        }
        __syncthreads();
    }

    // ---- phase 2: y2 at centers, x3 = y2 @ W2 + b2 (f32 VALU) ----
    if (tid < 256) {
        int c = tid >> 7, j = tid & 127;
        float acc = (c ? sc1s : sc0s) * x2s[c][j];
        int nc = c ? n1s : n0s;
        int off = 2 + (c ? n0s : 0);
        for (int k = 0; k < nc; k++) acc += Scoef[off + k] * x2s[off + k][j];
        y2s[c][j] = acc;
    }
    __syncthreads();
    if (tid < 256) {
        int c = tid >> 7, j = tid & 127;
        float acc = b2[j];
#pragma unroll 4
        for (int k = 0; k < H; k++) acc += y2s[c][k] * W2[(size_t)k * H + j];
        x3s[c][j] = acc;
    }
    __syncthreads();

    // ---- phase 3: hadamard + MLP head ----
    if (tid < 128) {
        int j = tid;
        float h = l1b[j];
#pragma unroll 4
        for (int k = 0; k < H; k++)
            h += (x3s[0][k] * x3s[1][k]) * l1w[(size_t)k * H + j];
        float tval = fmaxf(h, 0.f) * l2w[j];
#pragma unroll
        for (int d = 32; d > 0; d >>= 1) tval += __shfl_xor(tval, d);
        if (lane == 0) hpart[wv] = tval;
    }
    __syncthreads();
    if (tid == 0) out[g] = hpart[0] + hpart[1] + l2b[0];
}

extern "C" void kernel_launch(void* const* d_in, const int* in_sizes, int n_in,
                              void* d_out, int out_size, void* d_ws, size_t ws_size,
                              hipStream_t stream) {
    const int*   z    = (const int*)d_in[0];
    const int*   esrc = (const int*)d_in[1];
    const int*   edst = ((const int*)d_in[1]) + N_EDGES;
    const int*   mask = (const int*)d_in[3];
    const float* ztab = (const float*)d_in[4];
    const float* W0   = (const float*)d_in[5];
    const float* b0   = (const float*)d_in[6];
    const float* W1   = (const float*)d_in[7];
    const float* b1   = (const float*)d_in[8];
    const float* W2   = (const float*)d_in[9];
    const float* b2   = (const float*)d_in[10];
    const float* l1w  = (const float*)d_in[11];
    const float* l1b  = (const float*)d_in[12];
    const float* l2w  = (const float*)d_in[13];
    const float* l2b  = (const float*)d_in[14];
    float* out = (float*)d_out;

    char* w = (char*)d_ws;
    size_t o = 0;
    auto carve = [&](size_t bytes) { char* p = w + o; o = (o + bytes + 255) & ~(size_t)255; return p; };
    int*            fill = (int*)carve((size_t)N_NODES * 4);     // must be zeroed
    const size_t zero_span = o;
    int*            ell  = (int*)carve((size_t)N_NODES * ELL_CAP * 4);
    unsigned short* Wp   = (unsigned short*)carve((size_t)16384 * 2);   // W1 bf16 frags
    unsigned short* T0   = (unsigned short*)carve((size_t)MAX_Z * H * 2);

    hipMemsetAsync(d_ws, 0, zero_span, stream);
    // pass 1: ELL build (4-edge ILP) + T0 GEMM + W1 pack
    k_scan<<<SB + 63 + 8, 256, 0, stream>>>(esrc, edst, mask, fill, ell,
                                            ztab, W0, W1, Wp, T0);
    // pass 2: everything else, one block per graph
    k_fused<<<N_GRAPHS, 512, 0, stream>>>(z, T0, ell, fill, Wp, b0, b1,
                                          W2, b2, l1w, l1b, l2w, l2b, out);
}